// Round 2
// baseline (330.748 us; speedup 1.0000x reference)
//
#include <hip/hip_runtime.h>
#include <math.h>

// Masked sparsemax via Michelot/Newton active-set iteration (no sort).
// One WAVE (64 lanes) per row; 32 elements per lane live in registers.
// No LDS, no __syncthreads: cross-lane reduce via shuffle butterflies,
// active-set count via __ballot + scalar popcount (runs on the SALU pipe).

constexpr int D     = 2048;
constexpr int LANES = 64;
constexpr int EPT   = D / LANES;       // 32 elements per lane
constexpr int RPB   = 4;               // rows (waves) per 256-thread block
constexpr int TPB   = RPB * LANES;

__global__ __launch_bounds__(TPB) void sparsemax_kernel(
    const float* __restrict__ x,
    const int*   __restrict__ mask,
    float*       __restrict__ out)
{
    const int    wid  = threadIdx.x >> 6;
    const int    lane = threadIdx.x & 63;
    const size_t row  = (size_t)blockIdx.x * RPB + wid;
    const size_t base = row * D + (size_t)lane * EPT;

    // ---- Load 32 elements/lane: 8x float4 + 8x int4, per-lane contiguous.
    // 64 lanes x 16 B = 16 dense 64B lines per instruction (fully coalesced).
    float z[EPT];
    float S = 0.0f;          // sum of active z (lane-partial)
    int   C = 0;             // active count (wave-uniform via ballot)
    #pragma unroll
    for (int i = 0; i < EPT / 4; ++i) {
        const float4 a = ((const float4*)(x    + base))[i];
        const int4   m = ((const int4*)  (mask + base))[i];
        z[4*i + 0] = m.x ? a.x : -INFINITY;
        z[4*i + 1] = m.y ? a.y : -INFINITY;
        z[4*i + 2] = m.z ? a.z : -INFINITY;
        z[4*i + 3] = m.w ? a.w : -INFINITY;
        S += m.x ? a.x : 0.0f;
        S += m.y ? a.y : 0.0f;
        S += m.z ? a.z : 0.0f;
        S += m.w ? a.w : 0.0f;
        C += __popcll(__ballot(m.x != 0));
        C += __popcll(__ballot(m.y != 0));
        C += __popcll(__ballot(m.z != 0));
        C += __popcll(__ballot(m.w != 0));
    }
    // Butterfly-reduce S across the wave (C is already wave-uniform).
    #pragma unroll
    for (int off = 32; off > 0; off >>= 1)
        S += __shfl_xor(S, off, 64);

    float theta;
    if (C == 0) {
        theta = INFINITY;    // all masked -> output all zeros
    } else {
        theta = (S - 1.0f) / (float)C;   // Newton step from full active set
        int prevC = C;
        for (int it = 0; it < 64; ++it) {
            float s = 0.0f;  // lane-partial sum of max(z - theta, 0)
            int   c = 0;     // wave-uniform count of z > theta
            #pragma unroll
            for (int k = 0; k < EPT; ++k) {
                const float d = z[k] - theta;
                s += fmaxf(d, 0.0f);
                c += __popcll(__ballot(d > 0.0f));
            }
            if (c == prevC) break;       // set stable -> theta is exact
            #pragma unroll
            for (int off = 32; off > 0; off >>= 1)
                s += __shfl_xor(s, off, 64);
            theta += (s - 1.0f) / (float)c;
            prevC = c;
        }
    }

    // p = max(z - theta, 0); masked lanes (z = -inf) give exactly 0.
    #pragma unroll
    for (int i = 0; i < EPT / 4; ++i) {
        float4 o;
        o.x = fmaxf(z[4*i + 0] - theta, 0.0f);
        o.y = fmaxf(z[4*i + 1] - theta, 0.0f);
        o.z = fmaxf(z[4*i + 2] - theta, 0.0f);
        o.w = fmaxf(z[4*i + 3] - theta, 0.0f);
        ((float4*)(out + base))[i] = o;
    }
}

extern "C" void kernel_launch(void* const* d_in, const int* in_sizes, int n_in,
                              void* d_out, int out_size, void* d_ws, size_t ws_size,
                              hipStream_t stream) {
    const float* x    = (const float*)d_in[0];
    const int*   mask = (const int*)  d_in[1];
    float*       out  = (float*)d_out;
    const int n_rows = in_sizes[0] / D;
    sparsemax_kernel<<<n_rows / RPB, TPB, 0, stream>>>(x, mask, out);
}

// Round 4
// 325.078 us; speedup vs baseline: 1.0174x; 1.0174x over previous
//
#include <hip/hip_runtime.h>
#include <math.h>

// Masked sparsemax via Michelot/Newton active-set iteration (no sort).
// One WAVE (64 lanes) per row; 32 elements per lane live in registers.
// No LDS, no __syncthreads: cross-lane reduce via shuffle butterflies,
// active-set count via __ballot + scalar popcount (SALU pipe).
//
// Layout: INTERLEAVED. Lane l holds float4 vectors {i*64 + l} of the row
// (lane stride 16 B) so every global load/store instruction covers one dense
// 1 KiB segment. Round-2's per-lane-contiguous layout (128 B lane stride)
// caused 4x transaction amplification and capped HBM at ~2.2 TB/s.

constexpr int D     = 2048;
constexpr int LANES = 64;
constexpr int VPL   = D / 4 / LANES;   // float4 vectors per lane = 8
constexpr int RPB   = 4;               // rows (waves) per 256-thread block
constexpr int TPB   = RPB * LANES;

typedef __attribute__((ext_vector_type(4))) float nfloat4;  // native vec for nontemporal store

__global__ __launch_bounds__(TPB) void sparsemax_kernel(
    const float* __restrict__ x,
    const int*   __restrict__ mask,
    float*       __restrict__ out)
{
    const int    wid  = threadIdx.x >> 6;
    const int    lane = threadIdx.x & 63;
    const size_t row  = (size_t)blockIdx.x * RPB + wid;
    const size_t rb   = row * D;

    const float4* __restrict__ xv = (const float4*)(x    + rb);
    const int4*   __restrict__ mv = (const int4*)  (mask + rb);
    nfloat4*      __restrict__ ov = (nfloat4*)     (out  + rb);

    float z[4 * VPL];
    float S = 0.0f;          // sum of active z (lane-partial)
    int   C = 0;             // active count (wave-uniform via ballot)
    #pragma unroll
    for (int i = 0; i < VPL; ++i) {
        const float4 a = xv[i * LANES + lane];
        const int4   m = mv[i * LANES + lane];
        z[4*i + 0] = m.x ? a.x : -INFINITY;
        z[4*i + 1] = m.y ? a.y : -INFINITY;
        z[4*i + 2] = m.z ? a.z : -INFINITY;
        z[4*i + 3] = m.w ? a.w : -INFINITY;
        S += m.x ? a.x : 0.0f;
        S += m.y ? a.y : 0.0f;
        S += m.z ? a.z : 0.0f;
        S += m.w ? a.w : 0.0f;
        C += __popcll(__ballot(m.x != 0));
        C += __popcll(__ballot(m.y != 0));
        C += __popcll(__ballot(m.z != 0));
        C += __popcll(__ballot(m.w != 0));
    }
    // Butterfly-reduce S across the wave (C is already wave-uniform).
    #pragma unroll
    for (int off = 32; off > 0; off >>= 1)
        S += __shfl_xor(S, off, 64);

    float theta;
    if (C == 0) {
        theta = INFINITY;    // all masked -> output all zeros
    } else {
        theta = (S - 1.0f) / (float)C;   // Newton step from full active set
        int prevC = C;
        for (int it = 0; it < 64; ++it) {
            float s = 0.0f;  // lane-partial sum of max(z - theta, 0)
            int   c = 0;     // wave-uniform count of z > theta
            #pragma unroll
            for (int k = 0; k < 4 * VPL; ++k) {
                const float d = z[k] - theta;
                s += fmaxf(d, 0.0f);
                c += __popcll(__ballot(d > 0.0f));
            }
            if (c == prevC) break;       // set stable -> theta is exact
            #pragma unroll
            for (int off = 32; off > 0; off >>= 1)
                s += __shfl_xor(s, off, 64);
            theta += (s - 1.0f) / (float)c;
            prevC = c;
        }
    }

    // p = max(z - theta, 0); masked lanes (z = -inf) give exactly 0.
    // Nontemporal: out is never re-read, keep L2/L3 for the inputs.
    #pragma unroll
    for (int i = 0; i < VPL; ++i) {
        nfloat4 o;
        o.x = fmaxf(z[4*i + 0] - theta, 0.0f);
        o.y = fmaxf(z[4*i + 1] - theta, 0.0f);
        o.z = fmaxf(z[4*i + 2] - theta, 0.0f);
        o.w = fmaxf(z[4*i + 3] - theta, 0.0f);
        __builtin_nontemporal_store(o, &ov[i * LANES + lane]);
    }
}

extern "C" void kernel_launch(void* const* d_in, const int* in_sizes, int n_in,
                              void* d_out, int out_size, void* d_ws, size_t ws_size,
                              hipStream_t stream) {
    const float* x    = (const float*)d_in[0];
    const int*   mask = (const int*)  d_in[1];
    float*       out  = (float*)d_out;
    const int n_rows = in_sizes[0] / D;
    sparsemax_kernel<<<n_rows / RPB, TPB, 0, stream>>>(x, mask, out);
}